// Round 1
// baseline (83.123 us; speedup 1.0000x reference)
//
#include <hip/hip_runtime.h>

// Problem: B=32, L=512 -> N = 16384 flattened scores.
// loss = sum_{i: yt=1, j: yt=0} max(0, 1 - yp_i + yp_j) / (n_pos * n_neg)
//
// Strategy (round 1, correctness-first brute force):
//   - Fold masks into sentinels: c_i = (pos) ? 1 - yp_i : -1e30
//                                q_j = (neg) ? yp_j     : -1e30
//     then term = max(0, c_i + q_j) is exactly pos_i*neg_j*hinge (sentinel sums
//     stay ~-1e30/-2e30, well inside fp32 range -> clamp to 0, no NaN).
//   - 2D tile grid: 64 i-chunks (256 threads, 1 i each) x 8 j-chunks (2048 j
//     staged in LDS, broadcast reads). 512 blocks saturate 256 CUs.
//   - Per-thread 4 accumulators, wave shuffle reduce, one atomicAdd per block.
//   - Finalize kernel: count n_pos, out = num / (n_pos * n_neg).

#define N_TOTAL 16384
#define TJ 2048
#define BLOCK 256

__global__ void __launch_bounds__(BLOCK) auc_pair_kernel(
    const int* __restrict__ yt, const float* __restrict__ yp,
    float* __restrict__ num_acc) {
  __shared__ float qs[TJ];
  const int tid = threadIdx.x;
  const int i = blockIdx.x * BLOCK + tid;
  const int j0 = blockIdx.y * TJ;

  // Stage the q tile: 2048 elems, 256 threads -> 8 each, float4-vectorized.
  {
    int k = tid * 8;
    int j = j0 + k;
    int4 t4a = *(const int4*)(yt + j);
    float4 p4a = *(const float4*)(yp + j);
    int4 t4b = *(const int4*)(yt + j + 4);
    float4 p4b = *(const float4*)(yp + j + 4);
    float4 qa, qb;
    qa.x = (t4a.x == 0) ? p4a.x : -1e30f;
    qa.y = (t4a.y == 0) ? p4a.y : -1e30f;
    qa.z = (t4a.z == 0) ? p4a.z : -1e30f;
    qa.w = (t4a.w == 0) ? p4a.w : -1e30f;
    qb.x = (t4b.x == 0) ? p4b.x : -1e30f;
    qb.y = (t4b.y == 0) ? p4b.y : -1e30f;
    qb.z = (t4b.z == 0) ? p4b.z : -1e30f;
    qb.w = (t4b.w == 0) ? p4b.w : -1e30f;
    *(float4*)(qs + k) = qa;
    *(float4*)(qs + k + 4) = qb;
  }

  const float c = (yt[i] == 1) ? (1.0f - yp[i]) : -1e30f;
  __syncthreads();

  float a0 = 0.f, a1 = 0.f, a2 = 0.f, a3 = 0.f;
#pragma unroll 4
  for (int jj = 0; jj < TJ; jj += 4) {
    float4 q = *(const float4*)(qs + jj);  // wave-uniform addr -> LDS broadcast
    a0 += fmaxf(0.f, c + q.x);
    a1 += fmaxf(0.f, c + q.y);
    a2 += fmaxf(0.f, c + q.z);
    a3 += fmaxf(0.f, c + q.w);
  }
  float sum = (a0 + a1) + (a2 + a3);

  // wave64 shuffle reduction
#pragma unroll
  for (int off = 32; off > 0; off >>= 1) sum += __shfl_down(sum, off, 64);

  __shared__ float wsum[BLOCK / 64];
  if ((tid & 63) == 0) wsum[tid >> 6] = sum;
  __syncthreads();
  if (tid == 0) {
    float s = (wsum[0] + wsum[1]) + (wsum[2] + wsum[3]);
    atomicAdd(num_acc, s);  // device-scope by default on gfx950
  }
}

__global__ void __launch_bounds__(BLOCK) auc_finalize(
    const int* __restrict__ yt, const float* __restrict__ num_acc,
    float* __restrict__ out) {
  const int tid = threadIdx.x;
  int cnt = 0;
  for (int i = tid * 4; i < N_TOTAL; i += BLOCK * 4) {
    int4 t4 = *(const int4*)(yt + i);
    cnt += (t4.x == 1) + (t4.y == 1) + (t4.z == 1) + (t4.w == 1);
  }
#pragma unroll
  for (int off = 32; off > 0; off >>= 1) cnt += __shfl_down(cnt, off, 64);

  __shared__ int wc[BLOCK / 64];
  if ((tid & 63) == 0) wc[tid >> 6] = cnt;
  __syncthreads();
  if (tid == 0) {
    int npos = (wc[0] + wc[1]) + (wc[2] + wc[3]);
    float nneg = (float)(N_TOTAL - npos);
    out[0] = num_acc[0] / ((float)npos * nneg);
  }
}

extern "C" void kernel_launch(void* const* d_in, const int* in_sizes, int n_in,
                              void* d_out, int out_size, void* d_ws,
                              size_t ws_size, hipStream_t stream) {
  const int* yt = (const int*)d_in[0];    // y_true, int32, 16384
  const float* yp = (const float*)d_in[1];  // y_pred, float32, 16384
  float* out = (float*)d_out;             // scalar f32
  float* num_acc = (float*)d_ws;          // ws is re-poisoned 0xAA -> zero it

  hipMemsetAsync(d_ws, 0, sizeof(float), stream);

  dim3 grid(N_TOTAL / BLOCK, N_TOTAL / TJ);  // 64 x 8 = 512 blocks
  auc_pair_kernel<<<grid, BLOCK, 0, stream>>>(yt, yp, num_acc);
  auc_finalize<<<1, BLOCK, 0, stream>>>(yt, num_acc, out);
}